// Round 1
// baseline (243.165 us; speedup 1.0000x reference)
//
#include <hip/hip_runtime.h>
#include <hip/hip_bf16.h>

typedef __attribute__((ext_vector_type(8))) short bf16x8;
typedef __attribute__((ext_vector_type(4))) float f32x4;

__device__ __forceinline__ ushort f2bf(float f) {
  union { float f; unsigned u; } v; v.f = f;
  unsigned r = v.u + 0x7FFFu + ((v.u >> 16) & 1u);
  return (ushort)(r >> 16);
}

// ---------------------------------------------------------------- prep kernels
__global__ void __launch_bounds__(256) cast_h_kernel(const float* __restrict__ src,
                                                     ushort* __restrict__ dst) {
  int i = (blockIdx.x * 256 + threadIdx.x) * 8;
  float4 a = *(const float4*)(src + i);
  float4 b = *(const float4*)(src + i + 4);
  uint4 o;
  o.x = f2bf(a.x) | ((unsigned)f2bf(a.y) << 16);
  o.y = f2bf(a.z) | ((unsigned)f2bf(a.w) << 16);
  o.z = f2bf(b.x) | ((unsigned)f2bf(b.y) << 16);
  o.w = f2bf(b.z) | ((unsigned)f2bf(b.w) << 16);
  *(uint4*)(dst + i) = o;
}

// Wqkv_t[j][d], j = m*192 + which*64 + dk  (Bt layout: row=output col, col=K dim)
__global__ void __launch_bounds__(256) pack_wqkv_kernel(const float* __restrict__ WQ,
                                                        const float* __restrict__ WK,
                                                        const float* __restrict__ WV,
                                                        ushort* __restrict__ dst) {
  int t = blockIdx.x * 256 + threadIdx.x;   // < 1536*512
  int j = t >> 9, d = t & 511;
  int m = j / 192, r = j % 192, which = r >> 6, dk = r & 63;
  const float* W = (which == 0) ? WQ : (which == 1) ? WK : WV;
  dst[t] = f2bf(W[(m * 512 + d) * 64 + dk]);
}

// Wo_t[j][mv] = W_O[m][v][j]
__global__ void __launch_bounds__(256) pack_wo_kernel(const float* __restrict__ WO,
                                                      ushort* __restrict__ dst) {
  int t = blockIdx.x * 256 + threadIdx.x;   // < 512*512
  int j = t >> 9, mv = t & 511;
  dst[t] = f2bf(WO[mv * 512 + j]);
}

// ---------------------------------------------------------------- GEMM (A @ Bt)
// A [Mrows][Kdim] bf16 row-major, Bt [Ncols][Kdim] bf16 row-major.
// EPI==0: C fp32 [Mrows][Ncols].  EPI==1: scatter bf16 to Q/K/V [B*M][1024][64].
template <int EPI>
__global__ void __launch_bounds__(256) gemm_bt_kernel(
    const ushort* __restrict__ A, const ushort* __restrict__ Bt,
    float* __restrict__ C, int Kdim, int Ncols,
    ushort* __restrict__ Qo, ushort* __restrict__ Ko, ushort* __restrict__ Vo) {
  __shared__ __align__(16) ushort As[128][72];
  __shared__ __align__(16) ushort Bs[128][72];
  const int tid = threadIdx.x;
  const int lane = tid & 63, w = tid >> 6;
  const int wr = w >> 1, wc = w & 1;
  const int brow = blockIdx.y * 128, bcol = blockIdx.x * 128;

  f32x4 acc[4][4];
  const f32x4 z4 = {0.f, 0.f, 0.f, 0.f};
#pragma unroll
  for (int i = 0; i < 4; ++i)
#pragma unroll
    for (int j = 0; j < 4; ++j) acc[i][j] = z4;

  for (int k0 = 0; k0 < Kdim; k0 += 64) {
    __syncthreads();
#pragma unroll
    for (int i = 0; i < 4; ++i) {
      int c = tid + i * 256;             // 0..1023
      int row = c >> 3, cc = (c & 7) * 8;
      *(uint4*)&As[row][cc] = *(const uint4*)(A + (size_t)(brow + row) * Kdim + k0 + cc);
      *(uint4*)&Bs[row][cc] = *(const uint4*)(Bt + (size_t)(bcol + row) * Kdim + k0 + cc);
    }
    __syncthreads();
#pragma unroll
    for (int kk = 0; kk < 64; kk += 32) {
      bf16x8 a[4], b[4];
#pragma unroll
      for (int i = 0; i < 4; ++i)
        a[i] = *(const bf16x8*)&As[wr * 64 + i * 16 + (lane & 15)][kk + (lane >> 4) * 8];
#pragma unroll
      for (int j = 0; j < 4; ++j)
        b[j] = *(const bf16x8*)&Bs[wc * 64 + j * 16 + (lane & 15)][kk + (lane >> 4) * 8];
#pragma unroll
      for (int i = 0; i < 4; ++i)
#pragma unroll
        for (int j = 0; j < 4; ++j)
          acc[i][j] = __builtin_amdgcn_mfma_f32_16x16x32_bf16(a[i], b[j], acc[i][j], 0, 0, 0);
    }
  }

#pragma unroll
  for (int i = 0; i < 4; ++i) {
    int row0 = brow + wr * 64 + i * 16 + (lane >> 4) * 4;
#pragma unroll
    for (int j = 0; j < 4; ++j) {
      int col = bcol + wc * 64 + j * 16 + (lane & 15);
      if (EPI == 0) {
#pragma unroll
        for (int q = 0; q < 4; ++q)
          C[(size_t)(row0 + q) * Ncols + col] = acc[i][j][q];
      } else {
        int m = col / 192, r = col % 192, which = r >> 6, dk = r & 63;
        ushort* base = (which == 0) ? Qo : (which == 1) ? Ko : Vo;
#pragma unroll
        for (int q = 0; q < 4; ++q) {
          int row = row0 + q;
          int b = row >> 10, n = row & 1023;
          base[(size_t)((b * 8 + m) * 1024 + n) * 64 + dk] = f2bf(acc[i][j][q]);
        }
      }
    }
  }
}

// ---------------------------------------------------------------- V transpose
// V [bm][n][64] -> Vt [bm][v][1024]
__global__ void __launch_bounds__(256) transpose_v_kernel(const ushort* __restrict__ V,
                                                          ushort* __restrict__ Vt) {
  __shared__ __align__(16) ushort T[64][72];
  int bm = blockIdx.x >> 4, nt = blockIdx.x & 15;
  const ushort* src = V + (size_t)bm * 65536 + nt * 64 * 64;
  int tid = threadIdx.x;
#pragma unroll
  for (int i = 0; i < 2; ++i) {
    int c = tid + i * 256;               // 0..511
    int row = c >> 3, cc = (c & 7) * 8;
    *(uint4*)&T[row][cc] = *(const uint4*)(src + c * 8);
  }
  __syncthreads();
  int v = tid >> 2, nn0 = (tid & 3) * 16;
  ushort tmp[16];
#pragma unroll
  for (int k = 0; k < 16; ++k) tmp[k] = T[nn0 + k][v];
  ushort* dst = Vt + (size_t)bm * 65536 + v * 1024 + nt * 64 + nn0;
  *(uint4*)(dst + 0) = *(uint4*)&tmp[0];
  *(uint4*)(dst + 8) = *(uint4*)&tmp[8];
}

// ---------------------------------------------------------------- flash attention
// Q,K [bm][n][64] bf16; Vt [bm][v][1024] bf16; Hp [b][n][m*64+v] bf16.
__global__ void __launch_bounds__(256) attn_kernel(const ushort* __restrict__ Q,
                                                   const ushort* __restrict__ K,
                                                   const ushort* __restrict__ Vt,
                                                   ushort* __restrict__ Hp) {
  __shared__ __align__(16) ushort Ps[128][72];   // Q tile first, then P tiles
  __shared__ __align__(16) ushort Ks[64][72];
  __shared__ __align__(16) ushort Vs[64][72];
  const int bm = blockIdx.x >> 3, qt = blockIdx.x & 7;
  const int b = bm >> 3, m = bm & 7;
  const int tid = threadIdx.x, lane = tid & 63, w = tid >> 6;
  const ushort* Qp = Q + (size_t)bm * 65536;
  const ushort* Kp = K + (size_t)bm * 65536;
  const ushort* Vp = Vt + (size_t)bm * 65536;
  const int qbase = qt * 128;

  // stage Q tile [128][64] and hoist A-frags to registers
#pragma unroll
  for (int i = 0; i < 4; ++i) {
    int c = tid + i * 256;
    int row = c >> 3, cc = (c & 7) * 8;
    *(uint4*)&Ps[row][cc] = *(const uint4*)(Qp + qbase * 64 + c * 8);
  }
  __syncthreads();
  bf16x8 qa[2][2];
#pragma unroll
  for (int i = 0; i < 2; ++i)
#pragma unroll
    for (int kk = 0; kk < 2; ++kk)
      qa[i][kk] = *(const bf16x8*)&Ps[w * 32 + i * 16 + (lane & 15)][kk * 32 + (lane >> 4) * 8];
  __syncthreads();

  float mrun[2][4], lrun[2][4];
  f32x4 oacc[2][4];
  const f32x4 z4 = {0.f, 0.f, 0.f, 0.f};
#pragma unroll
  for (int i = 0; i < 2; ++i)
#pragma unroll
    for (int q = 0; q < 4; ++q) { mrun[i][q] = -1e30f; lrun[i][q] = 0.f; }
#pragma unroll
  for (int i = 0; i < 2; ++i)
#pragma unroll
    for (int j = 0; j < 4; ++j) oacc[i][j] = z4;

  for (int kt = 0; kt < 16; ++kt) {
    const int n0 = kt * 64;
    // stage K tile [64][64] and Vt tile [64 v][64 n]
#pragma unroll
    for (int i = 0; i < 2; ++i) {
      int c = tid + i * 256;             // 0..511
      int row = c >> 3, cc = (c & 7) * 8;
      *(uint4*)&Ks[row][cc] = *(const uint4*)(Kp + n0 * 64 + c * 8);
      *(uint4*)&Vs[row][cc] = *(const uint4*)(Vp + row * 1024 + n0 + cc);
    }
    __syncthreads();

    // S = (Q Kt) — wave computes rows w*32..+31, all 64 key-cols
    f32x4 s[2][4];
#pragma unroll
    for (int i = 0; i < 2; ++i)
#pragma unroll
      for (int j = 0; j < 4; ++j) s[i][j] = z4;
#pragma unroll
    for (int kk = 0; kk < 2; ++kk) {
      bf16x8 kb[4];
#pragma unroll
      for (int j = 0; j < 4; ++j)
        kb[j] = *(const bf16x8*)&Ks[j * 16 + (lane & 15)][kk * 32 + (lane >> 4) * 8];
#pragma unroll
      for (int i = 0; i < 2; ++i)
#pragma unroll
        for (int j = 0; j < 4; ++j)
          s[i][j] = __builtin_amdgcn_mfma_f32_16x16x32_bf16(qa[i][kk], kb[j], s[i][j], 0, 0, 0);
    }

    // online softmax (rows live in 16-lane groups: row=(lane>>4)*4+q, col=lane&15)
    float pf[2][4][4];
#pragma unroll
    for (int i = 0; i < 2; ++i) {
#pragma unroll
      for (int q = 0; q < 4; ++q) {
        float mx = -1e30f;
#pragma unroll
        for (int j = 0; j < 4; ++j) {
          float vv = s[i][j][q] * 0.125f;
          pf[i][j][q] = vv;
          mx = fmaxf(mx, vv);
        }
        mx = fmaxf(mx, __shfl_xor(mx, 1));
        mx = fmaxf(mx, __shfl_xor(mx, 2));
        mx = fmaxf(mx, __shfl_xor(mx, 4));
        mx = fmaxf(mx, __shfl_xor(mx, 8));
        float mnew = fmaxf(mrun[i][q], mx);
        float sc = __expf(mrun[i][q] - mnew);
        float rs = 0.f;
#pragma unroll
        for (int j = 0; j < 4; ++j) {
          float p = __expf(pf[i][j][q] - mnew);
          pf[i][j][q] = p;
          rs += p;
        }
        rs += __shfl_xor(rs, 1);
        rs += __shfl_xor(rs, 2);
        rs += __shfl_xor(rs, 4);
        rs += __shfl_xor(rs, 8);
        lrun[i][q] = lrun[i][q] * sc + rs;
        mrun[i][q] = mnew;
#pragma unroll
        for (int j = 0; j < 4; ++j) oacc[i][j][q] *= sc;
      }
    }

    // P -> LDS (each wave writes only its own 32 rows)
#pragma unroll
    for (int i = 0; i < 2; ++i)
#pragma unroll
      for (int j = 0; j < 4; ++j)
#pragma unroll
        for (int q = 0; q < 4; ++q)
          Ps[w * 32 + i * 16 + (lane >> 4) * 4 + q][j * 16 + (lane & 15)] = f2bf(pf[i][j][q]);
    __syncthreads();

    // O += P @ Vt  (A = P rows, Bt = Vs)
#pragma unroll
    for (int kk = 0; kk < 2; ++kk) {
      bf16x8 pa[2], vb[4];
#pragma unroll
      for (int i = 0; i < 2; ++i)
        pa[i] = *(const bf16x8*)&Ps[w * 32 + i * 16 + (lane & 15)][kk * 32 + (lane >> 4) * 8];
#pragma unroll
      for (int j = 0; j < 4; ++j)
        vb[j] = *(const bf16x8*)&Vs[j * 16 + (lane & 15)][kk * 32 + (lane >> 4) * 8];
#pragma unroll
      for (int i = 0; i < 2; ++i)
#pragma unroll
        for (int j = 0; j < 4; ++j)
          oacc[i][j] = __builtin_amdgcn_mfma_f32_16x16x32_bf16(pa[i], vb[j], oacc[i][j], 0, 0, 0);
    }
    __syncthreads();
  }

  // finalize: divide by l, store to Hp[b][n][m*64+v]
#pragma unroll
  for (int i = 0; i < 2; ++i)
#pragma unroll
    for (int q = 0; q < 4; ++q) {
      int n = qbase + w * 32 + i * 16 + (lane >> 4) * 4 + q;
      float inv = 1.0f / lrun[i][q];
      size_t rowoff = ((size_t)b * 1024 + n) * 512 + m * 64;
#pragma unroll
      for (int j = 0; j < 4; ++j)
        Hp[rowoff + j * 16 + (lane & 15)] = f2bf(oacc[i][j][q] * inv);
    }
}

// ---------------------------------------------------------------- launch
extern "C" void kernel_launch(void* const* d_in, const int* in_sizes, int n_in,
                              void* d_out, int out_size, void* d_ws, size_t ws_size,
                              hipStream_t stream) {
  const float* H  = (const float*)d_in[0];
  const float* WQ = (const float*)d_in[1];
  const float* WK = (const float*)d_in[2];
  const float* WV = (const float*)d_in[3];
  const float* WO = (const float*)d_in[4];
  float* out = (float*)d_out;

  // workspace carve (ushort elements); total ~98 MB
  ushort* ws   = (ushort*)d_ws;
  ushort* Hb   = ws;                         // 16384*512
  ushort* Wqkv = Hb + 16384 * 512;           // 1536*512
  ushort* Wo   = Wqkv + 1536 * 512;          // 512*512
  ushort* Qb   = Wo + 512 * 512;             // 128*1024*64
  ushort* Kb   = Qb + 128 * 1024 * 64;
  ushort* Vb   = Kb + 128 * 1024 * 64;
  ushort* Vtb  = Vb + 128 * 1024 * 64;
  ushort* Hp   = Vtb + 128 * 1024 * 64;      // 16384*512

  cast_h_kernel<<<4096, 256, 0, stream>>>(H, Hb);
  pack_wqkv_kernel<<<3072, 256, 0, stream>>>(WQ, WK, WV, Wqkv);
  pack_wo_kernel<<<1024, 256, 0, stream>>>(WO, Wo);
  gemm_bt_kernel<1><<<dim3(12, 128), 256, 0, stream>>>(Hb, Wqkv, nullptr, 512, 1536,
                                                       Qb, Kb, Vb);
  transpose_v_kernel<<<2048, 256, 0, stream>>>(Vb, Vtb);
  attn_kernel<<<1024, 256, 0, stream>>>(Qb, Kb, Vtb, Hp);
  gemm_bt_kernel<0><<<dim3(4, 128), 256, 0, stream>>>(Hp, Wo, out, 512, 512,
                                                      nullptr, nullptr, nullptr);
}

// Round 2
// 137.606 us; speedup vs baseline: 1.7671x; 1.7671x over previous
//
#include <hip/hip_runtime.h>
#include <hip/hip_bf16.h>

typedef __attribute__((ext_vector_type(8))) short bf16x8;
typedef __attribute__((ext_vector_type(4))) float f32x4;
typedef __attribute__((ext_vector_type(16))) float f32x16;
typedef __attribute__((ext_vector_type(2))) unsigned uint2v;

__device__ __forceinline__ ushort f2bf(float f) {
  union { float f; unsigned u; } v; v.f = f;
  unsigned r = v.u + 0x7FFFu + ((v.u >> 16) & 1u);
  return (ushort)(r >> 16);
}

__device__ __forceinline__ float exp2_(float x) {
#if __has_builtin(__builtin_amdgcn_exp2f)
  return __builtin_amdgcn_exp2f(x);
#else
  return exp2f(x);
#endif
}

__device__ __forceinline__ unsigned cvtpk(float lo, float hi) {
  unsigned r;
  asm("v_cvt_pk_bf16_f32 %0, %1, %2" : "=v"(r) : "v"(lo), "v"(hi));
  return r;
}

// {r.x, r.y}: r.x[l<32]=a[l], r.x[l>=32]=b[l-32]; r.y[l<32]=a[l+32], r.y[l>=32]=b[l]
__device__ __forceinline__ uint2v lane32_swap(unsigned a, unsigned b) {
#if __has_builtin(__builtin_amdgcn_permlane32_swap)
  return __builtin_amdgcn_permlane32_swap(a, b, false, false);
#else
  unsigned sa = (unsigned)__shfl_xor((int)a, 32);
  unsigned sb = (unsigned)__shfl_xor((int)b, 32);
  bool lo = ((threadIdx.x & 32) == 0);
  uint2v r;
  r.x = lo ? a : sb;
  r.y = lo ? sa : b;
  return r;
#endif
}

// 0.125 * log2(e): fold softmax scale + exp->exp2 conversion into Q
#define QSCALE 0.18033688011112042f

// ---------------------------------------------------------------- prep kernels
__global__ void __launch_bounds__(256) cast_h_kernel(const float* __restrict__ src,
                                                     ushort* __restrict__ dst) {
  int i = (blockIdx.x * 256 + threadIdx.x) * 8;
  float4 a = *(const float4*)(src + i);
  float4 b = *(const float4*)(src + i + 4);
  uint4 o;
  o.x = f2bf(a.x) | ((unsigned)f2bf(a.y) << 16);
  o.y = f2bf(a.z) | ((unsigned)f2bf(a.w) << 16);
  o.z = f2bf(b.x) | ((unsigned)f2bf(b.y) << 16);
  o.w = f2bf(b.z) | ((unsigned)f2bf(b.w) << 16);
  *(uint4*)(dst + i) = o;
}

__global__ void __launch_bounds__(256) pack_wqkv_kernel(const float* __restrict__ WQ,
                                                        const float* __restrict__ WK,
                                                        const float* __restrict__ WV,
                                                        ushort* __restrict__ dst) {
  int t = blockIdx.x * 256 + threadIdx.x;   // < 1536*512
  int j = t >> 9, d = t & 511;
  int m = j / 192, r = j % 192, which = r >> 6, dk = r & 63;
  const float* W = (which == 0) ? WQ : (which == 1) ? WK : WV;
  dst[t] = f2bf(W[(m * 512 + d) * 64 + dk]);
}

__global__ void __launch_bounds__(256) pack_wo_kernel(const float* __restrict__ WO,
                                                      ushort* __restrict__ dst) {
  int t = blockIdx.x * 256 + threadIdx.x;   // < 512*512
  int j = t >> 9, mv = t & 511;
  dst[t] = f2bf(WO[mv * 512 + j]);
}

// ---------------------------------------------------------------- GEMM (A @ Bt)
template <int EPI>
__global__ void __launch_bounds__(256) gemm_bt_kernel(
    const ushort* __restrict__ A, const ushort* __restrict__ Bt,
    float* __restrict__ C, int Kdim, int Ncols,
    ushort* __restrict__ Qo, ushort* __restrict__ Ko, ushort* __restrict__ Vo) {
  __shared__ __align__(16) ushort As[128][72];
  __shared__ __align__(16) ushort Bs[128][72];
  const int tid = threadIdx.x;
  const int lane = tid & 63, w = tid >> 6;
  const int wr = w >> 1, wc = w & 1;
  const int brow = blockIdx.y * 128, bcol = blockIdx.x * 128;

  f32x4 acc[4][4];
  const f32x4 z4 = {0.f, 0.f, 0.f, 0.f};
#pragma unroll
  for (int i = 0; i < 4; ++i)
#pragma unroll
    for (int j = 0; j < 4; ++j) acc[i][j] = z4;

  for (int k0 = 0; k0 < Kdim; k0 += 64) {
    __syncthreads();
#pragma unroll
    for (int i = 0; i < 4; ++i) {
      int c = tid + i * 256;             // 0..1023
      int row = c >> 3, cc = (c & 7) * 8;
      *(uint4*)&As[row][cc] = *(const uint4*)(A + (size_t)(brow + row) * Kdim + k0 + cc);
      *(uint4*)&Bs[row][cc] = *(const uint4*)(Bt + (size_t)(bcol + row) * Kdim + k0 + cc);
    }
    __syncthreads();
#pragma unroll
    for (int kk = 0; kk < 64; kk += 32) {
      bf16x8 a[4], b[4];
#pragma unroll
      for (int i = 0; i < 4; ++i)
        a[i] = *(const bf16x8*)&As[wr * 64 + i * 16 + (lane & 15)][kk + (lane >> 4) * 8];
#pragma unroll
      for (int j = 0; j < 4; ++j)
        b[j] = *(const bf16x8*)&Bs[wc * 64 + j * 16 + (lane & 15)][kk + (lane >> 4) * 8];
#pragma unroll
      for (int i = 0; i < 4; ++i)
#pragma unroll
        for (int j = 0; j < 4; ++j)
          acc[i][j] = __builtin_amdgcn_mfma_f32_16x16x32_bf16(a[i], b[j], acc[i][j], 0, 0, 0);
    }
  }

#pragma unroll
  for (int i = 0; i < 4; ++i) {
    int row0 = brow + wr * 64 + i * 16 + (lane >> 4) * 4;
#pragma unroll
    for (int j = 0; j < 4; ++j) {
      int col = bcol + wc * 64 + j * 16 + (lane & 15);
      if (EPI == 0) {
#pragma unroll
        for (int q = 0; q < 4; ++q)
          C[(size_t)(row0 + q) * Ncols + col] = acc[i][j][q];
      } else {
        int m = col / 192, r = col % 192, which = r >> 6, dk = r & 63;
        ushort* base = (which == 0) ? Qo : (which == 1) ? Ko : Vo;
        float cs = (which == 0) ? QSCALE : 1.0f;
#pragma unroll
        for (int q = 0; q < 4; ++q) {
          int row = row0 + q;
          int b = row >> 10, n = row & 1023;
          base[(size_t)((b * 8 + m) * 1024 + n) * 64 + dk] = f2bf(acc[i][j][q] * cs);
        }
      }
    }
  }
}

// ---------------------------------------------------------------- V transpose
__global__ void __launch_bounds__(256) transpose_v_kernel(const ushort* __restrict__ V,
                                                          ushort* __restrict__ Vt) {
  __shared__ __align__(16) ushort T[64][72];
  int bm = blockIdx.x >> 4, nt = blockIdx.x & 15;
  const ushort* src = V + (size_t)bm * 65536 + nt * 64 * 64;
  int tid = threadIdx.x;
#pragma unroll
  for (int i = 0; i < 2; ++i) {
    int c = tid + i * 256;               // 0..511
    int row = c >> 3, cc = (c & 7) * 8;
    *(uint4*)&T[row][cc] = *(const uint4*)(src + c * 8);
  }
  __syncthreads();
  int v = tid >> 2, nn0 = (tid & 3) * 16;
  ushort tmp[16];
#pragma unroll
  for (int k = 0; k < 16; ++k) tmp[k] = T[nn0 + k][v];
  ushort* dst = Vt + (size_t)bm * 65536 + v * 1024 + nt * 64 + nn0;
  *(uint4*)(dst + 0) = *(uint4*)&tmp[0];
  *(uint4*)(dst + 8) = *(uint4*)&tmp[8];
}

// ---------------------------------------------------------------- flash attention v2
// Swapped QK^T (S^T = K·Q^T), in-register softmax, O^T = V^T·P.
// Q,K [bm][n][64] bf16 (Q pre-scaled by QSCALE); Vt [bm][v][1024] bf16.
// Hp [b][n][m*64+v] bf16.
__global__ void __launch_bounds__(256, 2) attn_kernel(const ushort* __restrict__ Q,
                                                      const ushort* __restrict__ K,
                                                      const ushort* __restrict__ Vt,
                                                      ushort* __restrict__ Hp) {
  __shared__ __align__(16) ushort Ks[2][64 * 64];
  __shared__ __align__(16) ushort Vs[2][64 * 64];

  // XCD-aware swizzle: 512 blocks, 8 XCDs -> all 4 q-tiles of a head on one XCD
  int wk = (blockIdx.x & 7) * 64 + (blockIdx.x >> 3);
  const int bm = wk >> 2, qt = wk & 3;
  const int b = bm >> 3, m = bm & 7;
  const int tid = threadIdx.x, lane = tid & 63, w = tid >> 6;
  const int hi = lane >> 5, l31 = lane & 31;
  const ushort* Qp = Q + (size_t)bm * 65536;
  const ushort* Kp = K + (size_t)bm * 65536;
  const ushort* Vp = Vt + (size_t)bm * 65536;
  const int qw = qt * 256 + w * 64;   // wave's query base (64 queries, 2 subtiles)

  // Q B-frags: qb[qs][s] = Q[qw + qs*32 + l31][s*16 + hi*8 .. +7]
  bf16x8 qb[2][4];
#pragma unroll
  for (int qs = 0; qs < 2; ++qs)
#pragma unroll
    for (int s = 0; s < 4; ++s)
      qb[qs][s] = *(const bf16x8*)(Qp + (size_t)(qw + qs * 32 + l31) * 64 + s * 16 + hi * 8);

  f32x16 oacc[2][2];
#pragma unroll
  for (int qs = 0; qs < 2; ++qs)
#pragma unroll
    for (int vj = 0; vj < 2; ++vj)
#pragma unroll
      for (int r = 0; r < 16; ++r) oacc[qs][vj][r] = 0.f;
  float mrun[2] = {-1e30f, -1e30f}, lrun[2] = {0.f, 0.f};

  // staging map: thread -> (row sr, 32B chunk at elem sc4), XOR-swizzled dest
  const int sr = tid >> 2, sc4 = (tid & 3) << 4;
  const unsigned bo0 = ((unsigned)(sc4 * 2)) ^ (((unsigned)(sr & 7)) << 4);

  { // prologue: stage tile 0 into buf 0
    uint4 k0 = *(const uint4*)(Kp + (size_t)sr * 64 + sc4);
    uint4 k1 = *(const uint4*)(Kp + (size_t)sr * 64 + sc4 + 8);
    uint4 v0 = *(const uint4*)(Vp + (size_t)sr * 1024 + sc4);
    uint4 v1 = *(const uint4*)(Vp + (size_t)sr * 1024 + sc4 + 8);
    char* kd = (char*)&Ks[0][sr * 64];
    char* vd = (char*)&Vs[0][sr * 64];
    *(uint4*)(kd + bo0) = k0; *(uint4*)(kd + (bo0 ^ 16)) = k1;
    *(uint4*)(vd + bo0) = v0; *(uint4*)(vd + (bo0 ^ 16)) = v1;
  }
  __syncthreads();

  int cur = 0;
  for (int kt = 0; kt < 16; ++kt) {
    // T14: issue next tile's global loads before compute
    uint4 k0, k1, v0, v1;
    const bool pf = (kt < 15);
    if (pf) {
      int n0 = (kt + 1) * 64;
      k0 = *(const uint4*)(Kp + (size_t)(n0 + sr) * 64 + sc4);
      k1 = *(const uint4*)(Kp + (size_t)(n0 + sr) * 64 + sc4 + 8);
      v0 = *(const uint4*)(Vp + (size_t)sr * 1024 + n0 + sc4);
      v1 = *(const uint4*)(Vp + (size_t)sr * 1024 + n0 + sc4 + 8);
    }

    // K A-frags (XOR-swizzled ds_read_b128)
    const ushort* kbase = &Ks[cur][0];
    bf16x8 kA[2][4];
#pragma unroll
    for (int ja = 0; ja < 2; ++ja) {
      int row = ja * 32 + l31;
      const char* kr = (const char*)(kbase + row * 64);
#pragma unroll
      for (int s = 0; s < 4; ++s)
        kA[ja][s] = *(const bf16x8*)(kr + (((unsigned)(s * 32 + hi * 16)) ^ (((unsigned)(row & 7)) << 4)));
    }

    // S^T = K · Q^T  (lane l owns query l31; rows = keys)
    f32x16 st[2][2];
#pragma unroll
    for (int qs = 0; qs < 2; ++qs)
#pragma unroll
      for (int ja = 0; ja < 2; ++ja) {
#pragma unroll
        for (int r = 0; r < 16; ++r) st[qs][ja][r] = 0.f;
#pragma unroll
        for (int s = 0; s < 4; ++s)
          st[qs][ja] = __builtin_amdgcn_mfma_f32_32x32x16_bf16(kA[ja][s], qb[qs][s], st[qs][ja], 0, 0, 0);
      }

    // in-register online softmax + P packing (per query subtile)
    bf16x8 pb[2][4];
#pragma unroll
    for (int qs = 0; qs < 2; ++qs) {
      float tm[16];
#pragma unroll
      for (int r = 0; r < 16; ++r) tm[r] = fmaxf(st[qs][0][r], st[qs][1][r]);
#pragma unroll
      for (int sd = 8; sd >= 1; sd >>= 1)
#pragma unroll
        for (int r = 0; r < sd; ++r) tm[r] = fmaxf(tm[r], tm[r + sd]);
      float mx = fmaxf(tm[0], __shfl_xor(tm[0], 32));
      float mnew = fmaxf(mrun[qs], mx);
      float scal = exp2_(mrun[qs] - mnew);
      mrun[qs] = mnew;
#pragma unroll
      for (int ja = 0; ja < 2; ++ja)
#pragma unroll
        for (int r = 0; r < 16; ++r)
          st[qs][ja][r] = exp2_(st[qs][ja][r] - mnew);
      float ts[16];
#pragma unroll
      for (int r = 0; r < 16; ++r) ts[r] = st[qs][0][r] + st[qs][1][r];
#pragma unroll
      for (int sd = 8; sd >= 1; sd >>= 1)
#pragma unroll
        for (int r = 0; r < sd; ++r) ts[r] += ts[r + sd];
      float rs = ts[0] + __shfl_xor(ts[0], 32);
      lrun[qs] = lrun[qs] * scal + rs;
#pragma unroll
      for (int vj = 0; vj < 2; ++vj)
#pragma unroll
        for (int r = 0; r < 16; ++r) oacc[qs][vj][r] *= scal;

      // T12: cvt_pk + permlane32_swap -> PV B-frags, keys ks*16+hi*8+j
#pragma unroll
      for (int ja = 0; ja < 2; ++ja)
#pragma unroll
        for (int g = 0; g < 2; ++g) {
          unsigned x0 = cvtpk(st[qs][ja][g * 8 + 0], st[qs][ja][g * 8 + 1]);
          unsigned x1 = cvtpk(st[qs][ja][g * 8 + 2], st[qs][ja][g * 8 + 3]);
          unsigned y0 = cvtpk(st[qs][ja][g * 8 + 4], st[qs][ja][g * 8 + 5]);
          unsigned y1 = cvtpk(st[qs][ja][g * 8 + 6], st[qs][ja][g * 8 + 7]);
          uint2v s0 = lane32_swap(x0, y0);
          uint2v s1 = lane32_swap(x1, y1);
          uint4 wv; wv.x = s0.x; wv.y = s1.x; wv.z = s0.y; wv.w = s1.y;
          pb[qs][ja * 2 + g] = *(bf16x8*)&wv;
        }
    }

    // O^T += V^T · P
    const ushort* vbase = &Vs[cur][0];
#pragma unroll
    for (int vj = 0; vj < 2; ++vj) {
      int row = vj * 32 + l31;
      const char* vr = (const char*)(vbase + row * 64);
      bf16x8 va[4];
#pragma unroll
      for (int ks = 0; ks < 4; ++ks)
        va[ks] = *(const bf16x8*)(vr + (((unsigned)(ks * 32 + hi * 16)) ^ (((unsigned)(row & 7)) << 4)));
#pragma unroll
      for (int qs = 0; qs < 2; ++qs)
#pragma unroll
        for (int ks = 0; ks < 4; ++ks)
          oacc[qs][vj] = __builtin_amdgcn_mfma_f32_32x32x16_bf16(va[ks], pb[qs][ks], oacc[qs][vj], 0, 0, 0);
    }

    // write prefetched tile into other buffer
    if (pf) {
      char* kd = (char*)&Ks[cur ^ 1][sr * 64];
      char* vd = (char*)&Vs[cur ^ 1][sr * 64];
      *(uint4*)(kd + bo0) = k0; *(uint4*)(kd + (bo0 ^ 16)) = k1;
      *(uint4*)(vd + bo0) = v0; *(uint4*)(vd + (bo0 ^ 16)) = v1;
    }
    __syncthreads();
    cur ^= 1;
  }

  // finalize: O^T[v = vj*32 + (r&3)+8*(r>>2)+4*hi][q = qw+qs*32+l31] / l
#pragma unroll
  for (int qs = 0; qs < 2; ++qs) {
    float linv = 1.0f / lrun[qs];
    int q = qw + qs * 32 + l31;
    size_t ro = ((size_t)b * 1024 + q) * 512 + m * 64;
#pragma unroll
    for (int vj = 0; vj < 2; ++vj)
#pragma unroll
      for (int t4 = 0; t4 < 4; ++t4) {
        ushort4 o;
        o.x = f2bf(oacc[qs][vj][t4 * 4 + 0] * linv);
        o.y = f2bf(oacc[qs][vj][t4 * 4 + 1] * linv);
        o.z = f2bf(oacc[qs][vj][t4 * 4 + 2] * linv);
        o.w = f2bf(oacc[qs][vj][t4 * 4 + 3] * linv);
        *(ushort4*)(Hp + ro + vj * 32 + t4 * 8 + hi * 4) = o;
      }
  }
}

// ---------------------------------------------------------------- launch
extern "C" void kernel_launch(void* const* d_in, const int* in_sizes, int n_in,
                              void* d_out, int out_size, void* d_ws, size_t ws_size,
                              hipStream_t stream) {
  const float* H  = (const float*)d_in[0];
  const float* WQ = (const float*)d_in[1];
  const float* WK = (const float*)d_in[2];
  const float* WV = (const float*)d_in[3];
  const float* WO = (const float*)d_in[4];
  float* out = (float*)d_out;

  ushort* ws   = (ushort*)d_ws;
  ushort* Hb   = ws;                         // 16384*512
  ushort* Wqkv = Hb + 16384 * 512;           // 1536*512
  ushort* Wo   = Wqkv + 1536 * 512;          // 512*512
  ushort* Qb   = Wo + 512 * 512;             // 128*1024*64
  ushort* Kb   = Qb + 128 * 1024 * 64;
  ushort* Vb   = Kb + 128 * 1024 * 64;
  ushort* Vtb  = Vb + 128 * 1024 * 64;
  ushort* Hp   = Vtb + 128 * 1024 * 64;      // 16384*512

  cast_h_kernel<<<4096, 256, 0, stream>>>(H, Hb);
  pack_wqkv_kernel<<<3072, 256, 0, stream>>>(WQ, WK, WV, Wqkv);
  pack_wo_kernel<<<1024, 256, 0, stream>>>(WO, Wo);
  gemm_bt_kernel<1><<<dim3(12, 128), 256, 0, stream>>>(Hb, Wqkv, nullptr, 512, 1536,
                                                       Qb, Kb, Vb);
  transpose_v_kernel<<<2048, 256, 0, stream>>>(Vb, Vtb);
  attn_kernel<<<512, 256, 0, stream>>>(Qb, Kb, Vtb, Hp);
  gemm_bt_kernel<0><<<dim3(4, 128), 256, 0, stream>>>(Hp, Wo, out, 512, 512,
                                                      nullptr, nullptr, nullptr);
}